// Round 8
// baseline (367.713 us; speedup 1.0000x reference)
//
#include <hip/hip_runtime.h>

#define NNODES 50000
#define NEDGES 800000
#define DIM 96
#define LLDIM 64
#define NRELS 3            // metapath relations 0,1,2
#define SCAN_N (NRELS * NNODES)

// Frag-linear weight planes: per layer, hi plane then lo plane, 96*192 ushorts each.
// Element (c,k): ph=k/96, ks=(k%96)/32, g=(k%32)/8, kr=k%8, cg=c/16, r=c%15
// ushort offset = (((ph*3+ks)*6 + cg)*64 + g*16 + r)*8 + kr
#define BT_PLANE 18432                 // 96*192
#define BT_LAYER (2 * BT_PLANE)
#define BTL_PLANE 6144                 // 64*96 (final linear)
#define BT_LIN_OFF (3 * BT_LAYER)

typedef __attribute__((ext_vector_type(8))) short bf16x8;
typedef __attribute__((ext_vector_type(4))) float f32x4;

__device__ __forceinline__ unsigned short f2bf(float x) {
    union { float f; unsigned u; } v; v.f = x;
    unsigned r = v.u + 0x7fffu + ((v.u >> 16) & 1u);   // round-to-nearest-even
    return (unsigned short)(r >> 16);
}
__device__ __forceinline__ float bf2f(unsigned short b) {
    union { unsigned u; float f; } v; v.u = ((unsigned)b) << 16;
    return v.f;
}

// ---------------- CSR build ----------------

__global__ void hist_kernel(const int* __restrict__ ei, const int* __restrict__ et,
                            int* __restrict__ deg) {
    int e = blockIdx.x * 256 + threadIdx.x;
    if (e >= NEDGES) return;
    int r = et[e];
    if (r < NRELS) atomicAdd(&deg[r * NNODES + ei[e]], 1);
}

__global__ void scan1_kernel(const int* __restrict__ in, int* __restrict__ out,
                             int* __restrict__ partials, int n) {
    __shared__ int sdata[256];
    int tid = threadIdx.x;
    int base = blockIdx.x * 1024 + tid * 4;
    int v0 = (base + 0 < n) ? in[base + 0] : 0;
    int v1 = (base + 1 < n) ? in[base + 1] : 0;
    int v2 = (base + 2 < n) ? in[base + 2] : 0;
    int v3 = (base + 3 < n) ? in[base + 3] : 0;
    int tsum = v0 + v1 + v2 + v3;
    sdata[tid] = tsum;
    __syncthreads();
    for (int off = 1; off < 256; off <<= 1) {
        int x = sdata[tid];
        int y = (tid >= off) ? sdata[tid - off] : 0;
        __syncthreads();
        sdata[tid] = x + y;
        __syncthreads();
    }
    int excl = sdata[tid] - tsum;
    if (tid == 255) partials[blockIdx.x] = sdata[255];
    if (base + 0 < n) out[base + 0] = excl;
    excl += v0;
    if (base + 1 < n) out[base + 1] = excl;
    excl += v1;
    if (base + 2 < n) out[base + 2] = excl;
    excl += v2;
    if (base + 3 < n) out[base + 3] = excl;
}

__global__ void scan2_kernel(int* __restrict__ partials, int nb) {
    __shared__ int sdata[256];
    int tid = threadIdx.x;
    int v = (tid < nb) ? partials[tid] : 0;
    sdata[tid] = v;
    __syncthreads();
    for (int off = 1; off < 256; off <<= 1) {
        int x = sdata[tid];
        int y = (tid >= off) ? sdata[tid - off] : 0;
        __syncthreads();
        sdata[tid] = x + y;
        __syncthreads();
    }
    partials[tid] = sdata[tid] - v;   // exclusive
}

// adds block offsets AND initializes the fill cursor (row_end) = row_start.
__global__ void scan3_kernel(int* __restrict__ out, int* __restrict__ cursor,
                             const int* __restrict__ partials, int n) {
    int idx = blockIdx.x * 256 + threadIdx.x;
    if (idx < n) {
        int v = out[idx] + partials[idx >> 10];
        out[idx] = v;
        cursor[idx] = v;
    }
}

__global__ void fill_kernel(const int* __restrict__ ei, const int* __restrict__ et,
                            int* __restrict__ cursor, int* __restrict__ col) {
    int e = blockIdx.x * 256 + threadIdx.x;
    if (e >= NEDGES) return;
    int r = et[e];
    if (r < NRELS) {
        int pos = atomicAdd(&cursor[r * NNODES + ei[e]], 1);
        col[pos] = ei[NEDGES + e];
    }
}

// ---------------- weight prep (+ deg zeroing, saves a memset dispatch) ----------------

__global__ void prep_kernel(const float* __restrict__ w1, const float* __restrict__ root1,
                            const float* __restrict__ w2, const float* __restrict__ root2,
                            const float* __restrict__ lin_w,
                            unsigned short* __restrict__ bt, int* __restrict__ deg) {
    int idx = blockIdx.x * 256 + threadIdx.x;
    if (idx < SCAN_N) deg[idx] = 0;
    const int LYR = 96 * 192;
    if (idx < 3 * LYR) {
        int l = idx / LYR;
        int rem = idx % LYR;
        int c = rem / 192;
        int k = rem % 192;
        const float* Wm;
        const float* Rm;
        if (l == 0) { Wm = w1; Rm = root1; }
        else        { Wm = w2 + (size_t)l * 96 * 96; Rm = root2; }
        float v = (k < 96) ? Wm[(size_t)k * 96 + c] : Rm[(size_t)(k - 96) * 96 + c];
        unsigned short hi = f2bf(v);
        unsigned short lo = f2bf(v - bf2f(hi));
        int ph = k / 96, kk = k % 96;
        int ks = kk / 32, g = (kk & 31) >> 3, kr = k & 7;
        int cg = c >> 4, r = c & 15;
        size_t off = (((size_t)((ph * 3 + ks) * 6 + cg)) * 64 + g * 16 + r) * 8 + kr;
        unsigned short* base = bt + (size_t)l * BT_LAYER;
        base[off] = hi;
        base[BT_PLANE + off] = lo;
    } else if (idx < 3 * LYR + 64 * 96) {
        int rem = idx - 3 * LYR;
        int c = rem / 96;
        int k = rem % 96;
        float v = lin_w[(size_t)k * 64 + c];
        unsigned short hi = f2bf(v);
        unsigned short lo = f2bf(v - bf2f(hi));
        int ks = k / 32, g = (k & 31) >> 3, kr = k & 7;
        int cg = c >> 4, r = c & 15;
        size_t off = (((size_t)(ks * 4 + cg)) * 64 + g * 16 + r) * 8 + kr;
        unsigned short* base = bt + BT_LIN_OFF;
        base[off] = hi;
        base[BTL_PLANE + off] = lo;
    }
}

// ---------------- fused gather + layer GEMM (R4 structure, 256 thr) ----------------

__device__ __forceinline__ void gather_to_lds(
    const float* __restrict__ h, const int* __restrict__ rs, const int* __restrict__ re,
    const int* __restrict__ col, int n0, int tid,
    unsigned short* Ah, unsigned short* Al) {
    const int nd = tid >> 2;               // 0..63
    const int node = n0 + nd;
    const int cq4 = (tid & 3) * 24;        // col base (24 cols per thread)
    float a[24];
#pragma unroll
    for (int j = 0; j < 24; ++j) a[j] = 0.0f;
    int s = 0, e = 0;
    if (node < NNODES) { s = rs[node]; e = re[node]; }
    for (int i = s; i < e; ++i) {
        int d = col[i];
        const float* p = h + (size_t)d * DIM + cq4;
#pragma unroll
        for (int j6 = 0; j6 < 6; ++j6) {
            float4 v = *(const float4*)(p + j6 * 4);
            a[j6 * 4 + 0] += v.x; a[j6 * 4 + 1] += v.y;
            a[j6 * 4 + 2] += v.z; a[j6 * 4 + 3] += v.w;
        }
    }
    float scl = 1.0f / fmaxf((float)(e - s), 1.0f);
    int arow = nd * 104 + cq4;
#pragma unroll
    for (int jp = 0; jp < 12; ++jp) {
        float v0 = a[jp * 2] * scl, v1 = a[jp * 2 + 1] * scl;
        unsigned short h0 = f2bf(v0), h1 = f2bf(v1);
        unsigned short l0 = f2bf(v0 - bf2f(h0)), l1 = f2bf(v1 - bf2f(h1));
        *(unsigned int*)&Ah[arow + jp * 2] = (unsigned)h0 | ((unsigned)h1 << 16);
        *(unsigned int*)&Al[arow + jp * 2] = (unsigned)l0 | ((unsigned)l1 << 16);
    }
}

__device__ __forceinline__ void stage_h_to_lds(
    const float* __restrict__ src, int n0, int tid,
    unsigned short* Ah, unsigned short* Al) {
#pragma unroll
    for (int j = 0; j < 6; ++j) {
        int idx = tid + j * 256;           // 0..1535 float4s
        int nd = idx / 24;
        int kq = idx % 24;
        int node = n0 + nd;
        if (node >= NNODES) node = NNODES - 1;   // results discarded on store guard
        float4 v = *(const float4*)(src + (size_t)node * DIM + kq * 4);
        unsigned short h0 = f2bf(v.x), h1 = f2bf(v.y), h2 = f2bf(v.z), h3 = f2bf(v.w);
        *(ushort4*)&Ah[nd * 104 + kq * 4] = make_ushort4(h0, h1, h2, h3);
        unsigned short l0 = f2bf(v.x - bf2f(h0));
        unsigned short l1 = f2bf(v.y - bf2f(h1));
        unsigned short l2 = f2bf(v.z - bf2f(h2));
        unsigned short l3 = f2bf(v.w - bf2f(h3));
        *(ushort4*)&Al[nd * 104 + kq * 4] = make_ushort4(l0, l1, l2, l3);
    }
}

#define KS_LOOP(PH)                                                                     \
    _Pragma("unroll")                                                                   \
    for (int ks = 0; ks < 3; ++ks) {                                                    \
        const int ko = ks * 32 + g * 8;                                                 \
        bf16x8 a0h = *(const bf16x8*)&Ah[(rb_base + r) * 104 + ko];                     \
        bf16x8 a1h = *(const bf16x8*)&Ah[(rb_base + 16 + r) * 104 + ko];                \
        bf16x8 a0l = *(const bf16x8*)&Al[(rb_base + r) * 104 + ko];                     \
        bf16x8 a1l = *(const bf16x8*)&Al[(rb_base + 16 + r) * 104 + ko];                \
        const unsigned short* bks = bt + ((size_t)(((PH) * 3 + ks) * 6) * 64 + lane) * 8;\
        _Pragma("unroll")                                                               \
        for (int ct = 0; ct < 3; ++ct) {                                                \
            const unsigned short* bp = bks + (size_t)(cg_base + ct) * 512;              \
            bf16x8 bhv = *(const bf16x8*)bp;                                            \
            bf16x8 blv = *(const bf16x8*)(bp + BT_PLANE);                               \
            acc[0][ct] = __builtin_amdgcn_mfma_f32_16x16x32_bf16(a0h, bhv, acc[0][ct], 0, 0, 0); \
            acc[1][ct] = __builtin_amdgcn_mfma_f32_16x16x32_bf16(a1h, bhv, acc[1][ct], 0, 0, 0); \
            acc[0][ct] = __builtin_amdgcn_mfma_f32_16x16x32_bf16(a0l, bhv, acc[0][ct], 0, 0, 0); \
            acc[1][ct] = __builtin_amdgcn_mfma_f32_16x16x32_bf16(a1l, bhv, acc[1][ct], 0, 0, 0); \
            acc[0][ct] = __builtin_amdgcn_mfma_f32_16x16x32_bf16(a0h, blv, acc[0][ct], 0, 0, 0); \
            acc[1][ct] = __builtin_amdgcn_mfma_f32_16x16x32_bf16(a1h, blv, acc[1][ct], 0, 0, 0); \
        }                                                                               \
    }

__global__ __launch_bounds__(256) void layer_fused_kernel(
    const float* __restrict__ h, const int* __restrict__ rs, const int* __restrict__ re,
    const int* __restrict__ col, const unsigned short* __restrict__ bt,
    const float* __restrict__ b, float* __restrict__ out) {
    __shared__ unsigned short Ah[64 * 104];
    __shared__ unsigned short Al[64 * 104];
    const int tid = threadIdx.x;
    const int lane = tid & 63;
    const int w = tid >> 6;
    const int r = lane & 15;
    const int g = lane >> 4;
    const int rb_base = (w >> 1) * 32;
    const int cg_base = (w & 1) * 3;
    const int n0 = blockIdx.x * 64;

    // phase 0 A-operand: gathered neighbor mean, straight to LDS
    gather_to_lds(h, rs, re, col, n0, tid, Ah, Al);

    f32x4 acc[2][3];
#pragma unroll
    for (int i = 0; i < 2; ++i)
#pragma unroll
        for (int j = 0; j < 3; ++j) acc[i][j] = (f32x4){0.f, 0.f, 0.f, 0.f};

    __syncthreads();
    KS_LOOP(0)
    __syncthreads();                       // done reading phase-0 A
    stage_h_to_lds(h, n0, tid, Ah, Al);    // phase 1 A-operand: h tile
    __syncthreads();
    KS_LOOP(1)

    // epilogue: C/D layout: col = lane&15, row = g*4 + j
#pragma unroll
    for (int ct = 0; ct < 3; ++ct) {
        int colc = (cg_base + ct) * 16 + r;
        float bias = b[colc];
#pragma unroll
        for (int rbi = 0; rbi < 2; ++rbi) {
            int row0 = n0 + rb_base + rbi * 16 + g * 4;
#pragma unroll
            for (int j = 0; j < 4; ++j) {
                int node = row0 + j;
                if (node < NNODES)
                    out[(size_t)node * DIM + colc] = fmaxf(acc[rbi][ct][j] + bias, 0.0f);
            }
        }
    }
}

// ---------------- fused gather + layer 2 + final linear (256 threads) ----------------

__global__ __launch_bounds__(256) void layer2_final_kernel(
    const float* __restrict__ h, const int* __restrict__ rs, const int* __restrict__ re,
    const int* __restrict__ col, const unsigned short* __restrict__ bt,
    const float* __restrict__ b, const unsigned short* __restrict__ btl,
    const float* __restrict__ LB, float* __restrict__ out) {
    __shared__ unsigned short Ah[64 * 104];
    __shared__ unsigned short Al[64 * 104];
    const int tid = threadIdx.x;
    const int lane = tid & 63;
    const int w = tid >> 6;
    const int r = lane & 15;
    const int g = lane >> 4;
    const int rb_base = (w >> 1) * 32;
    const int cg_base = (w & 1) * 3;
    const int n0 = blockIdx.x * 64;

    gather_to_lds(h, rs, re, col, n0, tid, Ah, Al);

    f32x4 acc[2][3];
#pragma unroll
    for (int i = 0; i < 2; ++i)
#pragma unroll
        for (int j = 0; j < 3; ++j) acc[i][j] = (f32x4){0.f, 0.f, 0.f, 0.f};

    __syncthreads();
    KS_LOOP(0)
    __syncthreads();
    stage_h_to_lds(h, n0, tid, Ah, Al);
    __syncthreads();
    KS_LOOP(1)

    // h2 = relu(acc+bias) -> LDS bf16 hi/lo, layout [row][k]
    __syncthreads();                       // all waves done reading phase-1 A
#pragma unroll
    for (int ct = 0; ct < 3; ++ct) {
        int colc = (cg_base + ct) * 16 + r;
        float bias = b[colc];
#pragma unroll
        for (int rbi = 0; rbi < 2; ++rbi) {
            int row0 = rb_base + rbi * 16 + g * 4;
#pragma unroll
            for (int j = 0; j < 4; ++j) {
                float v = fmaxf(acc[rbi][ct][j] + bias, 0.0f);
                unsigned short hh = f2bf(v);
                unsigned short ll = f2bf(v - bf2f(hh));
                Ah[(row0 + j) * 104 + colc] = hh;
                Al[(row0 + j) * 104 + colc] = ll;
            }
        }
    }
    __syncthreads();

    // final GEMM: 64 cols, wave = 32 rows x 32 cols, K = 96 (from LDS h2)
    const int cgf = (w & 1) * 2;
    f32x4 accf[2][2];
#pragma unroll
    for (int i = 0; i < 2; ++i)
#pragma unroll
        for (int j = 0; j < 2; ++j) accf[i][j] = (f32x4){0.f, 0.f, 0.f, 0.f};

#pragma unroll
    for (int ks = 0; ks < 3; ++ks) {
        const int ko = ks * 32 + g * 8;
        bf16x8 a0h = *(const bf16x8*)&Ah[(rb_base + r) * 104 + ko];
        bf16x8 a1h = *(const bf16x8*)&Ah[(rb_base + 16 + r) * 104 + ko];
        bf16x8 a0l = *(const bf16x8*)&Al[(rb_base + r) * 104 + ko];
        bf16x8 a1l = *(const bf16x8*)&Al[(rb_base + 16 + r) * 104 + ko];
        const unsigned short* bks = btl + ((size_t)(ks * 4) * 64 + lane) * 8;
#pragma unroll
        for (int ct = 0; ct < 2; ++ct) {
            const unsigned short* bp = bks + (size_t)(cgf + ct) * 512;
            bf16x8 bhv = *(const bf16x8*)bp;
            bf16x8 blv = *(const bf16x8*)(bp + BTL_PLANE);
            accf[0][ct] = __builtin_amdgcn_mfma_f32_16x16x32_bf16(a0h, bhv, accf[0][ct], 0, 0, 0);
            accf[1][ct] = __builtin_amdgcn_mfma_f32_16x16x32_bf16(a1h, bhv, accf[1][ct], 0, 0, 0);
            accf[0][ct] = __builtin_amdgcn_mfma_f32_16x16x32_bf16(a0l, bhv, accf[0][ct], 0, 0, 0);
            accf[1][ct] = __builtin_amdgcn_mfma_f32_16x16x32_bf16(a1l, bhv, accf[1][ct], 0, 0, 0);
            accf[0][ct] = __builtin_amdgcn_mfma_f32_16x16x32_bf16(a0h, blv, accf[0][ct], 0, 0, 0);
            accf[1][ct] = __builtin_amdgcn_mfma_f32_16x16x32_bf16(a1h, blv, accf[1][ct], 0, 0, 0);
        }
    }

#pragma unroll
    for (int ct = 0; ct < 2; ++ct) {
        int colc = (cgf + ct) * 16 + r;
        float bias = LB[colc];
#pragma unroll
        for (int rbi = 0; rbi < 2; ++rbi) {
            int row0 = n0 + rb_base + rbi * 16 + g * 4;
#pragma unroll
            for (int j = 0; j < 4; ++j) {
                int node = row0 + j;
                if (node < NNODES)
                    out[(size_t)node * LLDIM + colc] = accf[rbi][ct][j] + bias;
            }
        }
    }
}

extern "C" void kernel_launch(void* const* d_in, const int* in_sizes, int n_in,
                              void* d_out, int out_size, void* d_ws, size_t ws_size,
                              hipStream_t stream) {
    const float* x     = (const float*)d_in[0];
    const int*   ei    = (const int*)d_in[1];
    const int*   et    = (const int*)d_in[2];
    const float* w1    = (const float*)d_in[3];
    const float* root1 = (const float*)d_in[4];
    const float* b1    = (const float*)d_in[5];
    const float* w2    = (const float*)d_in[6];
    const float* root2 = (const float*)d_in[7];
    const float* b2    = (const float*)d_in[8];
    const float* lin_w = (const float*)d_in[9];
    const float* lin_b = (const float*)d_in[10];

    float* bufA = (float*)d_ws;                      // N*96
    float* bufB = bufA + (size_t)NNODES * DIM;       // N*96
    int* deg       = (int*)(bufB + (size_t)NNODES * DIM);
    int* row_start = deg + SCAN_N;
    int* row_end   = row_start + SCAN_N;
    int* col       = row_end + SCAN_N;               // up to NEDGES
    int* partials  = col + NEDGES;                   // 256
    unsigned short* bt = (unsigned short*)(partials + 256);

    const int edge_blocks = (NEDGES + 255) / 256;
    const int scan_blocks = (SCAN_N + 1023) / 1024;  // 147
    const int node_tiles  = (NNODES + 63) / 64;      // 782
    const int prep_blocks = (SCAN_N + 255) / 256;

    // ---- weight prep + deg zero ----
    prep_kernel<<<prep_blocks, 256, 0, stream>>>(w1, root1, w2, root2, lin_w, bt, deg);

    // ---- CSR build ----
    hist_kernel<<<edge_blocks, 256, 0, stream>>>(ei, et, deg);
    scan1_kernel<<<scan_blocks, 256, 0, stream>>>(deg, row_start, partials, SCAN_N);
    scan2_kernel<<<1, 256, 0, stream>>>(partials, scan_blocks);
    scan3_kernel<<<(SCAN_N + 255) / 256, 256, 0, stream>>>(row_start, row_end, partials, SCAN_N);
    fill_kernel<<<edge_blocks, 256, 0, stream>>>(ei, et, row_end, col);

    // ---- Layer 0 (rel 0): x -> bufA ----
    layer_fused_kernel<<<node_tiles, 256, 0, stream>>>(
        x, row_start + 0 * NNODES, row_end + 0 * NNODES, col,
        bt + 0 * (size_t)BT_LAYER, b1, bufA);

    // ---- Layer 1 (rel 1): bufA -> bufB ----
    // MEASUREMENT ROUND: launched 7x (6 redundant, bit-identical result).
    // dur_us - 221.3 = 6 * (T_layer_warm + gap). Interpretation pre-committed
    // in the journal; revert to single launch next round.
    for (int rep = 0; rep < 7; ++rep) {
        layer_fused_kernel<<<node_tiles, 256, 0, stream>>>(
            bufA, row_start + 1 * NNODES, row_end + 1 * NNODES, col,
            bt + 1 * (size_t)BT_LAYER, b2, bufB);
    }

    // ---- Layer 2 (rel 2) + final linear: bufB -> d_out ----
    layer2_final_kernel<<<node_tiles, 256, 0, stream>>>(
        bufB, row_start + 2 * NNODES, row_end + 2 * NNODES, col,
        bt + 2 * (size_t)BT_LAYER, b2, bt + BT_LIN_OFF, lin_b, (float*)d_out);
}

// Round 9
// 248.090 us; speedup vs baseline: 1.4822x; 1.4822x over previous
//
#include <hip/hip_runtime.h>

#define NNODES 50000
#define NEDGES 800000
#define DIM 96
#define LLDIM 64
#define NRELS 3            // metapath relations 0,1,2
#define SCAN_N (NRELS * NNODES)
#define SCAN_BLOCKS ((SCAN_N + 1023) / 1024)   // 147

// Frag-linear weight planes: per layer, hi plane then lo plane, 96*192 ushorts each.
// Element (c,k): ph=k/96, ks=(k%96)/32, g=(k%32)/8, kr=k%8, cg=c/16, r=c%16
// ushort offset = (((ph*3+ks)*6 + cg)*64 + g*16 + r)*8 + kr
#define BT_PLANE 18432                 // 96*192
#define BT_LAYER (2 * BT_PLANE)
#define BTL_PLANE 6144                 // 64*96 (final linear)
#define BT_LIN_OFF (3 * BT_LAYER)
#define BT_TOTAL (3 * BT_LAYER + 2 * BTL_PLANE)   // 122880 ushorts

typedef __attribute__((ext_vector_type(8))) short bf16x8;
typedef __attribute__((ext_vector_type(4))) float f32x4;

__device__ __forceinline__ unsigned short f2bf(float x) {
    union { float f; unsigned u; } v; v.f = x;
    unsigned r = v.u + 0x7fffu + ((v.u >> 16) & 1u);   // round-to-nearest-even
    return (unsigned short)(r >> 16);
}
__device__ __forceinline__ float bf2f(unsigned short b) {
    union { unsigned u; float f; } v; v.u = ((unsigned)b) << 16;
    return v.f;
}

// ---------------- CSR build ----------------

__global__ void hist_kernel(const int* __restrict__ ei, const int* __restrict__ et,
                            int* __restrict__ deg) {
    int e = blockIdx.x * 256 + threadIdx.x;
    if (e >= NEDGES) return;
    int r = et[e];
    if (r < NRELS) atomicAdd(&deg[r * NNODES + ei[e]], 1);
}

// Single-dispatch exclusive scan over SCAN_N via decoupled lookback.
// Replaces scan1+scan2+scan3; also initializes the fill cursor (row_end).
// flags[bid]: (value<<32)|state, state 1 = aggregate ready, 2 = inclusive prefix.
// 147 blocks (< 256 CUs) -> all co-resident; ticket ensures lookback targets run.
__global__ void scan_fused_kernel(const int* __restrict__ in, int* __restrict__ out,
                                  int* __restrict__ cursor,
                                  unsigned long long* __restrict__ flags,
                                  int* __restrict__ ticket, int n) {
    __shared__ int sdata[256];
    __shared__ int sbid;
    __shared__ int sprefix;
    int tid = threadIdx.x;
    if (tid == 0) sbid = atomicAdd(ticket, 1);
    __syncthreads();
    int bid = sbid;
    int base = bid * 1024 + tid * 4;
    int v0 = (base + 0 < n) ? in[base + 0] : 0;
    int v1 = (base + 1 < n) ? in[base + 1] : 0;
    int v2 = (base + 2 < n) ? in[base + 2] : 0;
    int v3 = (base + 3 < n) ? in[base + 3] : 0;
    int tsum = v0 + v1 + v2 + v3;
    sdata[tid] = tsum;
    __syncthreads();
    for (int off = 1; off < 256; off <<= 1) {
        int x = sdata[tid];
        int y = (tid >= off) ? sdata[tid - off] : 0;
        __syncthreads();
        sdata[tid] = x + y;
        __syncthreads();
    }
    int excl = sdata[tid] - tsum;
    if (tid == 0) {
        int T = sdata[255];
        atomicExch(&flags[bid], ((unsigned long long)(unsigned)T << 32) | 1ULL);
        int prefix = 0;
        for (int j = bid - 1; j >= 0; --j) {
            unsigned long long f;
            do { f = atomicAdd(&flags[j], 0ULL); } while ((f & 3ULL) == 0ULL);
            prefix += (int)(f >> 32);
            if ((f & 3ULL) == 2ULL) break;
        }
        atomicExch(&flags[bid], ((unsigned long long)(unsigned)(prefix + T) << 32) | 2ULL);
        sprefix = prefix;
    }
    __syncthreads();
    excl += sprefix;
    if (base + 0 < n) { out[base + 0] = excl; cursor[base + 0] = excl; }
    excl += v0;
    if (base + 1 < n) { out[base + 1] = excl; cursor[base + 1] = excl; }
    excl += v1;
    if (base + 2 < n) { out[base + 2] = excl; cursor[base + 2] = excl; }
    excl += v2;
    if (base + 3 < n) { out[base + 3] = excl; cursor[base + 3] = excl; }
}

__global__ void fill_kernel(const int* __restrict__ ei, const int* __restrict__ et,
                            int* __restrict__ cursor, int* __restrict__ col) {
    int e = blockIdx.x * 256 + threadIdx.x;
    if (e >= NEDGES) return;
    int r = et[e];
    if (r < NRELS) {
        int pos = atomicAdd(&cursor[r * NNODES + ei[e]], 1);
        col[pos] = ei[NEDGES + e];
    }
}

// ---------------- weight prep (+ deg/flags/ticket zeroing) ----------------

__global__ void prep_kernel(const float* __restrict__ w1, const float* __restrict__ root1,
                            const float* __restrict__ w2, const float* __restrict__ root2,
                            const float* __restrict__ lin_w,
                            unsigned short* __restrict__ bt, int* __restrict__ deg,
                            unsigned long long* __restrict__ flags, int* __restrict__ ticket) {
    int idx = blockIdx.x * 256 + threadIdx.x;
    if (idx < SCAN_N) deg[idx] = 0;
    if (idx < 256) flags[idx] = 0ULL;
    if (idx == 300) *ticket = 0;
    const int LYR = 96 * 192;
    if (idx < 3 * LYR) {
        int l = idx / LYR;
        int rem = idx % LYR;
        int c = rem / 192;
        int k = rem % 192;
        const float* Wm;
        const float* Rm;
        if (l == 0) { Wm = w1; Rm = root1; }
        else        { Wm = w2 + (size_t)l * 96 * 96; Rm = root2; }
        float v = (k < 96) ? Wm[(size_t)k * 96 + c] : Rm[(size_t)(k - 96) * 96 + c];
        unsigned short hi = f2bf(v);
        unsigned short lo = f2bf(v - bf2f(hi));
        int ph = k / 96, kk = k % 96;
        int ks = kk / 32, g = (kk & 31) >> 3, kr = k & 7;
        int cg = c >> 4, r = c & 15;
        size_t off = (((size_t)((ph * 3 + ks) * 6 + cg)) * 64 + g * 16 + r) * 8 + kr;
        unsigned short* base = bt + (size_t)l * BT_LAYER;
        base[off] = hi;
        base[BT_PLANE + off] = lo;
    } else if (idx < 3 * LYR + 64 * 96) {
        int rem = idx - 3 * LYR;
        int c = rem / 96;
        int k = rem % 96;
        float v = lin_w[(size_t)k * 64 + c];
        unsigned short hi = f2bf(v);
        unsigned short lo = f2bf(v - bf2f(hi));
        int ks = k / 32, g = (k & 31) >> 3, kr = k & 7;
        int cg = c >> 4, r = c & 15;
        size_t off = (((size_t)(ks * 4 + cg)) * 64 + g * 16 + r) * 8 + kr;
        unsigned short* base = bt + BT_LIN_OFF;
        base[off] = hi;
        base[BTL_PLANE + off] = lo;
    }
}

// ---------------- fused gather + layer GEMM (R4 structure, 256 thr) ----------------
// Gather: 4 thr/node x 24 cols, neighbor loop 2-wide unrolled (dual accumulator
// sets -> 2 independent col->row L3 chains in flight, R3-proven).

__device__ __forceinline__ void gather_to_lds(
    const float* __restrict__ h, const int* __restrict__ rs, const int* __restrict__ re,
    const int* __restrict__ col, int n0, int tid,
    unsigned short* Ah, unsigned short* Al) {
    const int nd = tid >> 2;               // 0..63
    const int node = n0 + nd;
    const int cq4 = (tid & 3) * 24;        // col base (24 cols per thread)
    float a[24], c2[24];
#pragma unroll
    for (int j = 0; j < 24; ++j) { a[j] = 0.0f; c2[j] = 0.0f; }
    int s = 0, e = 0;
    if (node < NNODES) { s = rs[node]; e = re[node]; }
    int i = s;
    for (; i + 2 <= e; i += 2) {
        int d0 = col[i];
        int d1 = col[i + 1];
        const float* p0 = h + (size_t)d0 * DIM + cq4;
        const float* p1 = h + (size_t)d1 * DIM + cq4;
#pragma unroll
        for (int j6 = 0; j6 < 6; ++j6) {
            float4 u = *(const float4*)(p0 + j6 * 4);
            float4 v = *(const float4*)(p1 + j6 * 4);
            a[j6 * 4 + 0] += u.x; a[j6 * 4 + 1] += u.y;
            a[j6 * 4 + 2] += u.z; a[j6 * 4 + 3] += u.w;
            c2[j6 * 4 + 0] += v.x; c2[j6 * 4 + 1] += v.y;
            c2[j6 * 4 + 2] += v.z; c2[j6 * 4 + 3] += v.w;
        }
    }
    if (i < e) {
        int d = col[i];
        const float* p = h + (size_t)d * DIM + cq4;
#pragma unroll
        for (int j6 = 0; j6 < 6; ++j6) {
            float4 u = *(const float4*)(p + j6 * 4);
            a[j6 * 4 + 0] += u.x; a[j6 * 4 + 1] += u.y;
            a[j6 * 4 + 2] += u.z; a[j6 * 4 + 3] += u.w;
        }
    }
#pragma unroll
    for (int j = 0; j < 24; ++j) a[j] += c2[j];
    float scl = 1.0f / fmaxf((float)(e - s), 1.0f);
    int arow = nd * 104 + cq4;
#pragma unroll
    for (int jp = 0; jp < 12; ++jp) {
        float v0 = a[jp * 2] * scl, v1 = a[jp * 2 + 1] * scl;
        unsigned short h0 = f2bf(v0), h1 = f2bf(v1);
        unsigned short l0 = f2bf(v0 - bf2f(h0)), l1 = f2bf(v1 - bf2f(h1));
        *(unsigned int*)&Ah[arow + jp * 2] = (unsigned)h0 | ((unsigned)h1 << 16);
        *(unsigned int*)&Al[arow + jp * 2] = (unsigned)l0 | ((unsigned)l1 << 16);
    }
}

__device__ __forceinline__ void stage_h_to_lds(
    const float* __restrict__ src, int n0, int tid,
    unsigned short* Ah, unsigned short* Al) {
#pragma unroll
    for (int j = 0; j < 6; ++j) {
        int idx = tid + j * 256;           // 0..1535 float4s
        int nd = idx / 24;
        int kq = idx % 24;
        int node = n0 + nd;
        if (node >= NNODES) node = NNODES - 1;   // results discarded on store guard
        float4 v = *(const float4*)(src + (size_t)node * DIM + kq * 4);
        unsigned short h0 = f2bf(v.x), h1 = f2bf(v.y), h2 = f2bf(v.z), h3 = f2bf(v.w);
        *(ushort4*)&Ah[nd * 104 + kq * 4] = make_ushort4(h0, h1, h2, h3);
        unsigned short l0 = f2bf(v.x - bf2f(h0));
        unsigned short l1 = f2bf(v.y - bf2f(h1));
        unsigned short l2 = f2bf(v.z - bf2f(h2));
        unsigned short l3 = f2bf(v.w - bf2f(h3));
        *(ushort4*)&Al[nd * 104 + kq * 4] = make_ushort4(l0, l1, l2, l3);
    }
}

#define KS_LOOP(PH)                                                                     \
    _Pragma("unroll")                                                                   \
    for (int ks = 0; ks < 3; ++ks) {                                                    \
        const int ko = ks * 32 + g * 8;                                                 \
        bf16x8 a0h = *(const bf16x8*)&Ah[(rb_base + r) * 104 + ko];                     \
        bf16x8 a1h = *(const bf16x8*)&Ah[(rb_base + 16 + r) * 104 + ko];                \
        bf16x8 a0l = *(const bf16x8*)&Al[(rb_base + r) * 104 + ko];                     \
        bf16x8 a1l = *(const bf16x8*)&Al[(rb_base + 16 + r) * 104 + ko];                \
        const unsigned short* bks = bt + ((size_t)(((PH) * 3 + ks) * 6) * 64 + lane) * 8;\
        _Pragma("unroll")                                                               \
        for (int ct = 0; ct < 3; ++ct) {                                                \
            const unsigned short* bp = bks + (size_t)(cg_base + ct) * 512;              \
            bf16x8 bhv = *(const bf16x8*)bp;                                            \
            bf16x8 blv = *(const bf16x8*)(bp + BT_PLANE);                               \
            acc[0][ct] = __builtin_amdgcn_mfma_f32_16x16x32_bf16(a0h, bhv, acc[0][ct], 0, 0, 0); \
            acc[1][ct] = __builtin_amdgcn_mfma_f32_16x16x32_bf16(a1h, bhv, acc[1][ct], 0, 0, 0); \
            acc[0][ct] = __builtin_amdgcn_mfma_f32_16x16x32_bf16(a0l, bhv, acc[0][ct], 0, 0, 0); \
            acc[1][ct] = __builtin_amdgcn_mfma_f32_16x16x32_bf16(a1l, bhv, acc[1][ct], 0, 0, 0); \
            acc[0][ct] = __builtin_amdgcn_mfma_f32_16x16x32_bf16(a0h, blv, acc[0][ct], 0, 0, 0); \
            acc[1][ct] = __builtin_amdgcn_mfma_f32_16x16x32_bf16(a1h, blv, acc[1][ct], 0, 0, 0); \
        }                                                                               \
    }

__global__ __launch_bounds__(256) void layer_fused_kernel(
    const float* __restrict__ h, const int* __restrict__ rs, const int* __restrict__ re,
    const int* __restrict__ col, const unsigned short* __restrict__ bt,
    const float* __restrict__ b, float* __restrict__ out) {
    __shared__ unsigned short Ah[64 * 104];
    __shared__ unsigned short Al[64 * 104];
    const int tid = threadIdx.x;
    const int lane = tid & 63;
    const int w = tid >> 6;
    const int r = lane & 15;
    const int g = lane >> 4;
    const int rb_base = (w >> 1) * 32;
    const int cg_base = (w & 1) * 3;
    const int n0 = blockIdx.x * 64;

    // phase 0 A-operand: gathered neighbor mean, straight to LDS
    gather_to_lds(h, rs, re, col, n0, tid, Ah, Al);

    f32x4 acc[2][3];
#pragma unroll
    for (int i = 0; i < 2; ++i)
#pragma unroll
        for (int j = 0; j < 3; ++j) acc[i][j] = (f32x4){0.f, 0.f, 0.f, 0.f};

    __syncthreads();
    KS_LOOP(0)
    __syncthreads();                       // done reading phase-0 A
    stage_h_to_lds(h, n0, tid, Ah, Al);    // phase 1 A-operand: h tile
    __syncthreads();
    KS_LOOP(1)

    // epilogue: C/D layout: col = lane&15, row = g*4 + j
#pragma unroll
    for (int ct = 0; ct < 3; ++ct) {
        int colc = (cg_base + ct) * 16 + r;
        float bias = b[colc];
#pragma unroll
        for (int rbi = 0; rbi < 2; ++rbi) {
            int row0 = n0 + rb_base + rbi * 16 + g * 4;
#pragma unroll
            for (int j = 0; j < 4; ++j) {
                int node = row0 + j;
                if (node < NNODES)
                    out[(size_t)node * DIM + colc] = fmaxf(acc[rbi][ct][j] + bias, 0.0f);
            }
        }
    }
}

// ---------------- fused gather + layer 2 + final linear (256 threads) ----------------

__global__ __launch_bounds__(256) void layer2_final_kernel(
    const float* __restrict__ h, const int* __restrict__ rs, const int* __restrict__ re,
    const int* __restrict__ col, const unsigned short* __restrict__ bt,
    const float* __restrict__ b, const unsigned short* __restrict__ btl,
    const float* __restrict__ LB, float* __restrict__ out) {
    __shared__ unsigned short Ah[64 * 104];
    __shared__ unsigned short Al[64 * 104];
    const int tid = threadIdx.x;
    const int lane = tid & 63;
    const int w = tid >> 6;
    const int r = lane & 15;
    const int g = lane >> 4;
    const int rb_base = (w >> 1) * 32;
    const int cg_base = (w & 1) * 3;
    const int n0 = blockIdx.x * 64;

    gather_to_lds(h, rs, re, col, n0, tid, Ah, Al);

    f32x4 acc[2][3];
#pragma unroll
    for (int i = 0; i < 2; ++i)
#pragma unroll
        for (int j = 0; j < 3; ++j) acc[i][j] = (f32x4){0.f, 0.f, 0.f, 0.f};

    __syncthreads();
    KS_LOOP(0)
    __syncthreads();
    stage_h_to_lds(h, n0, tid, Ah, Al);
    __syncthreads();
    KS_LOOP(1)

    // h2 = relu(acc+bias) -> LDS bf16 hi/lo, layout [row][k]
    __syncthreads();                       // all waves done reading phase-1 A
#pragma unroll
    for (int ct = 0; ct < 3; ++ct) {
        int colc = (cg_base + ct) * 16 + r;
        float bias = b[colc];
#pragma unroll
        for (int rbi = 0; rbi < 2; ++rbi) {
            int row0 = rb_base + rbi * 16 + g * 4;
#pragma unroll
            for (int j = 0; j < 4; ++j) {
                float v = fmaxf(acc[rbi][ct][j] + bias, 0.0f);
                unsigned short hh = f2bf(v);
                unsigned short ll = f2bf(v - bf2f(hh));
                Ah[(row0 + j) * 104 + colc] = hh;
                Al[(row0 + j) * 104 + colc] = ll;
            }
        }
    }
    __syncthreads();

    // final GEMM: 64 cols, wave = 32 rows x 32 cols, K = 96 (from LDS h2)
    const int cgf = (w & 1) * 2;
    f32x4 accf[2][2];
#pragma unroll
    for (int i = 0; i < 2; ++i)
#pragma unroll
        for (int j = 0; j < 2; ++j) accf[i][j] = (f32x4){0.f, 0.f, 0.f, 0.f};

#pragma unroll
    for (int ks = 0; ks < 3; ++ks) {
        const int ko = ks * 32 + g * 8;
        bf16x8 a0h = *(const bf16x8*)&Ah[(rb_base + r) * 104 + ko];
        bf16x8 a1h = *(const bf16x8*)&Ah[(rb_base + 16 + r) * 104 + ko];
        bf16x8 a0l = *(const bf16x8*)&Al[(rb_base + r) * 104 + ko];
        bf16x8 a1l = *(const bf16x8*)&Al[(rb_base + 16 + r) * 104 + ko];
        const unsigned short* bks = btl + ((size_t)(ks * 4) * 64 + lane) * 8;
#pragma unroll
        for (int ct = 0; ct < 2; ++ct) {
            const unsigned short* bp = bks + (size_t)(cgf + ct) * 512;
            bf16x8 bhv = *(const bf16x8*)bp;
            bf16x8 blv = *(const bf16x8*)(bp + BTL_PLANE);
            accf[0][ct] = __builtin_amdgcn_mfma_f32_16x16x32_bf16(a0h, bhv, accf[0][ct], 0, 0, 0);
            accf[1][ct] = __builtin_amdgcn_mfma_f32_16x16x32_bf16(a1h, bhv, accf[1][ct], 0, 0, 0);
            accf[0][ct] = __builtin_amdgcn_mfma_f32_16x16x32_bf16(a0l, bhv, accf[0][ct], 0, 0, 0);
            accf[1][ct] = __builtin_amdgcn_mfma_f32_16x16x32_bf16(a1l, bhv, accf[1][ct], 0, 0, 0);
            accf[0][ct] = __builtin_amdgcn_mfma_f32_16x16x32_bf16(a0h, blv, accf[0][ct], 0, 0, 0);
            accf[1][ct] = __builtin_amdgcn_mfma_f32_16x16x32_bf16(a1h, blv, accf[1][ct], 0, 0, 0);
        }
    }

#pragma unroll
    for (int ct = 0; ct < 2; ++ct) {
        int colc = (cgf + ct) * 16 + r;
        float bias = LB[colc];
#pragma unroll
        for (int rbi = 0; rbi < 2; ++rbi) {
            int row0 = n0 + rb_base + rbi * 16 + g * 4;
#pragma unroll
            for (int j = 0; j < 4; ++j) {
                int node = row0 + j;
                if (node < NNODES)
                    out[(size_t)node * LLDIM + colc] = accf[rbi][ct][j] + bias;
            }
        }
    }
}

extern "C" void kernel_launch(void* const* d_in, const int* in_sizes, int n_in,
                              void* d_out, int out_size, void* d_ws, size_t ws_size,
                              hipStream_t stream) {
    const float* x     = (const float*)d_in[0];
    const int*   ei    = (const int*)d_in[1];
    const int*   et    = (const int*)d_in[2];
    const float* w1    = (const float*)d_in[3];
    const float* root1 = (const float*)d_in[4];
    const float* b1    = (const float*)d_in[5];
    const float* w2    = (const float*)d_in[6];
    const float* root2 = (const float*)d_in[7];
    const float* b2    = (const float*)d_in[8];
    const float* lin_w = (const float*)d_in[9];
    const float* lin_b = (const float*)d_in[10];

    float* bufA = (float*)d_ws;                      // N*96
    float* bufB = bufA + (size_t)NNODES * DIM;       // N*96
    int* deg       = (int*)(bufB + (size_t)NNODES * DIM);
    int* row_start = deg + SCAN_N;
    int* row_end   = row_start + SCAN_N;
    int* col       = row_end + SCAN_N;               // up to NEDGES
    int* partials  = col + NEDGES;                   // 256 (unused, kept for layout)
    unsigned short* bt = (unsigned short*)(partials + 256);
    unsigned long long* flags = (unsigned long long*)(bt + BT_TOTAL);  // 256 ull
    int* ticket = (int*)(flags + 256);

    const int edge_blocks = (NEDGES + 255) / 256;
    const int node_tiles  = (NNODES + 63) / 64;      // 782
    const int prep_blocks = (SCAN_N + 255) / 256;

    // ---- weight prep + deg/flags/ticket zero ----
    prep_kernel<<<prep_blocks, 256, 0, stream>>>(w1, root1, w2, root2, lin_w, bt, deg,
                                                 flags, ticket);

    // ---- CSR build: hist -> lookback scan (1 dispatch) -> fill ----
    hist_kernel<<<edge_blocks, 256, 0, stream>>>(ei, et, deg);
    scan_fused_kernel<<<SCAN_BLOCKS, 256, 0, stream>>>(deg, row_start, row_end,
                                                       flags, ticket, SCAN_N);
    fill_kernel<<<edge_blocks, 256, 0, stream>>>(ei, et, row_end, col);

    // ---- Layer 0 (rel 0): x -> bufA ----
    layer_fused_kernel<<<node_tiles, 256, 0, stream>>>(
        x, row_start + 0 * NNODES, row_end + 0 * NNODES, col,
        bt + 0 * (size_t)BT_LAYER, b1, bufA);

    // ---- Layer 1 (rel 1): bufA -> bufB ----
    layer_fused_kernel<<<node_tiles, 256, 0, stream>>>(
        bufA, row_start + 1 * NNODES, row_end + 1 * NNODES, col,
        bt + 1 * (size_t)BT_LAYER, b2, bufB);

    // ---- Layer 2 (rel 2) + final linear: bufB -> d_out ----
    layer2_final_kernel<<<node_tiles, 256, 0, stream>>>(
        bufB, row_start + 2 * NNODES, row_end + 2 * NNODES, col,
        bt + 2 * (size_t)BT_LAYER, b2, bt + BT_LIN_OFF, lin_b, (float*)d_out);
}

// Round 10
// 213.926 us; speedup vs baseline: 1.7189x; 1.1597x over previous
//
#include <hip/hip_runtime.h>

#define NNODES 50000
#define NEDGES 800000
#define DIM 96
#define LLDIM 64
#define NRELS 3            // metapath relations 0,1,2
#define SCAN_N (NRELS * NNODES)

// Frag-linear weight planes: per layer, hi plane then lo plane, 96*192 ushorts each.
// Element (c,k): ph=k/96, ks=(k%96)/32, g=(k%32)/8, kr=k%8, cg=c/16, r=c%16
// ushort offset = (((ph*3+ks)*6 + cg)*64 + g*16 + r)*8 + kr
#define BT_PLANE 18432                 // 96*192
#define BT_LAYER (2 * BT_PLANE)
#define BTL_PLANE 6144                 // 64*96 (final linear)
#define BT_LIN_OFF (3 * BT_LAYER)

typedef __attribute__((ext_vector_type(8))) short bf16x8;
typedef __attribute__((ext_vector_type(4))) float f32x4;

__device__ __forceinline__ unsigned short f2bf(float x) {
    union { float f; unsigned u; } v; v.f = x;
    unsigned r = v.u + 0x7fffu + ((v.u >> 16) & 1u);   // round-to-nearest-even
    return (unsigned short)(r >> 16);
}
__device__ __forceinline__ float bf2f(unsigned short b) {
    union { unsigned u; float f; } v; v.u = ((unsigned)b) << 16;
    return v.f;
}

// ---------------- CSR build ----------------

__global__ void hist_kernel(const int* __restrict__ ei, const int* __restrict__ et,
                            int* __restrict__ deg) {
    int e = blockIdx.x * 256 + threadIdx.x;
    if (e >= NEDGES) return;
    int r = et[e];
    if (r < NRELS) atomicAdd(&deg[r * NNODES + ei[e]], 1);
}

__global__ void scan1_kernel(const int* __restrict__ in, int* __restrict__ out,
                             int* __restrict__ partials, int n) {
    __shared__ int sdata[256];
    int tid = threadIdx.x;
    int base = blockIdx.x * 1024 + tid * 4;
    int v0 = (base + 0 < n) ? in[base + 0] : 0;
    int v1 = (base + 1 < n) ? in[base + 1] : 0;
    int v2 = (base + 2 < n) ? in[base + 2] : 0;
    int v3 = (base + 3 < n) ? in[base + 3] : 0;
    int tsum = v0 + v1 + v2 + v3;
    sdata[tid] = tsum;
    __syncthreads();
    for (int off = 1; off < 256; off <<= 1) {
        int x = sdata[tid];
        int y = (tid >= off) ? sdata[tid - off] : 0;
        __syncthreads();
        sdata[tid] = x + y;
        __syncthreads();
    }
    int excl = sdata[tid] - tsum;
    if (tid == 255) partials[blockIdx.x] = sdata[255];
    if (base + 0 < n) out[base + 0] = excl;
    excl += v0;
    if (base + 1 < n) out[base + 1] = excl;
    excl += v1;
    if (base + 2 < n) out[base + 2] = excl;
    excl += v2;
    if (base + 3 < n) out[base + 3] = excl;
}

// fused scan2+scan3: each block reduces partials[0..c-1] (c = blockIdx>>2 <= 146)
// in-block, adds to its chunk, and initializes the fill cursor (row_end).
__global__ void scan3_kernel(int* __restrict__ out, int* __restrict__ cursor,
                             const int* __restrict__ partials, int n) {
    __shared__ int sdata[256];
    int tid = threadIdx.x;
    int c = blockIdx.x >> 2;               // 1024-chunk index (4 blocks per chunk)
    sdata[tid] = (tid < c) ? partials[tid] : 0;
    __syncthreads();
    for (int off = 128; off > 0; off >>= 1) {
        if (tid < off) sdata[tid] += sdata[tid + off];
        __syncthreads();
    }
    int base = sdata[0];
    int idx = blockIdx.x * 256 + tid;
    if (idx < n) {
        int v = out[idx] + base;
        out[idx] = v;
        cursor[idx] = v;
    }
}

__global__ void fill_kernel(const int* __restrict__ ei, const int* __restrict__ et,
                            int* __restrict__ cursor, int* __restrict__ col) {
    int e = blockIdx.x * 256 + threadIdx.x;
    if (e >= NEDGES) return;
    int r = et[e];
    if (r < NRELS) {
        int pos = atomicAdd(&cursor[r * NNODES + ei[e]], 1);
        col[pos] = ei[NEDGES + e];
    }
}

// ---------------- weight prep (+ deg zeroing, saves a memset dispatch) ----------------

__global__ void prep_kernel(const float* __restrict__ w1, const float* __restrict__ root1,
                            const float* __restrict__ w2, const float* __restrict__ root2,
                            const float* __restrict__ lin_w,
                            unsigned short* __restrict__ bt, int* __restrict__ deg) {
    int idx = blockIdx.x * 256 + threadIdx.x;
    if (idx < SCAN_N) deg[idx] = 0;
    const int LYR = 96 * 192;
    if (idx < 3 * LYR) {
        int l = idx / LYR;
        int rem = idx % LYR;
        int c = rem / 192;
        int k = rem % 192;
        const float* Wm;
        const float* Rm;
        if (l == 0) { Wm = w1; Rm = root1; }
        else        { Wm = w2 + (size_t)l * 96 * 96; Rm = root2; }
        float v = (k < 96) ? Wm[(size_t)k * 96 + c] : Rm[(size_t)(k - 96) * 96 + c];
        unsigned short hi = f2bf(v);
        unsigned short lo = f2bf(v - bf2f(hi));
        int ph = k / 96, kk = k % 96;
        int ks = kk / 32, g = (kk & 31) >> 3, kr = k & 7;
        int cg = c >> 4, r = c & 15;
        size_t off = (((size_t)((ph * 3 + ks) * 6 + cg)) * 64 + g * 16 + r) * 8 + kr;
        unsigned short* base = bt + (size_t)l * BT_LAYER;
        base[off] = hi;
        base[BT_PLANE + off] = lo;
    } else if (idx < 3 * LYR + 64 * 96) {
        int rem = idx - 3 * LYR;
        int c = rem / 96;
        int k = rem % 96;
        float v = lin_w[(size_t)k * 64 + c];
        unsigned short hi = f2bf(v);
        unsigned short lo = f2bf(v - bf2f(hi));
        int ks = k / 32, g = (k & 31) >> 3, kr = k & 7;
        int cg = c >> 4, r = c & 15;
        size_t off = (((size_t)(ks * 4 + cg)) * 64 + g * 16 + r) * 8 + kr;
        unsigned short* base = bt + BT_LIN_OFF;
        base[off] = hi;
        base[BTL_PLANE + off] = lo;
    }
}

// ---------------- fused gather + layer GEMM (R4 structure, 256 thr) ----------------
// Gather: 4 thr/node x 24 cols; col-index PREFETCH (1 extra int reg) overlaps
// the next neighbor's index load with the current row loads. Sum order identical
// to R4 -> bit-identical output.

__device__ __forceinline__ void gather_to_lds(
    const float* __restrict__ h, const int* __restrict__ rs, const int* __restrict__ re,
    const int* __restrict__ col, int n0, int tid,
    unsigned short* Ah, unsigned short* Al) {
    const int nd = tid >> 2;               // 0..63
    const int node = n0 + nd;
    const int cq4 = (tid & 3) * 24;        // col base (24 cols per thread)
    float a[24];
#pragma unroll
    for (int j = 0; j < 24; ++j) a[j] = 0.0f;
    int s = 0, e = 0;
    if (node < NNODES) { s = rs[node]; e = re[node]; }
    int d_next = (s < e) ? col[s] : 0;
    for (int i = s; i < e; ++i) {
        int d = d_next;
        if (i + 1 < e) d_next = col[i + 1];
        const float* p = h + (size_t)d * DIM + cq4;
#pragma unroll
        for (int j6 = 0; j6 < 6; ++j6) {
            float4 v = *(const float4*)(p + j6 * 4);
            a[j6 * 4 + 0] += v.x; a[j6 * 4 + 1] += v.y;
            a[j6 * 4 + 2] += v.z; a[j6 * 4 + 3] += v.w;
        }
    }
    float scl = 1.0f / fmaxf((float)(e - s), 1.0f);
    int arow = nd * 104 + cq4;
#pragma unroll
    for (int jp = 0; jp < 12; ++jp) {
        float v0 = a[jp * 2] * scl, v1 = a[jp * 2 + 1] * scl;
        unsigned short h0 = f2bf(v0), h1 = f2bf(v1);
        unsigned short l0 = f2bf(v0 - bf2f(h0)), l1 = f2bf(v1 - bf2f(h1));
        *(unsigned int*)&Ah[arow + jp * 2] = (unsigned)h0 | ((unsigned)h1 << 16);
        *(unsigned int*)&Al[arow + jp * 2] = (unsigned)l0 | ((unsigned)l1 << 16);
    }
}

__device__ __forceinline__ void stage_h_to_lds(
    const float* __restrict__ src, int n0, int tid,
    unsigned short* Ah, unsigned short* Al) {
#pragma unroll
    for (int j = 0; j < 6; ++j) {
        int idx = tid + j * 256;           // 0..1535 float4s
        int nd = idx / 24;
        int kq = idx % 24;
        int node = n0 + nd;
        if (node >= NNODES) node = NNODES - 1;   // results discarded on store guard
        float4 v = *(const float4*)(src + (size_t)node * DIM + kq * 4);
        unsigned short h0 = f2bf(v.x), h1 = f2bf(v.y), h2 = f2bf(v.z), h3 = f2bf(v.w);
        *(ushort4*)&Ah[nd * 104 + kq * 4] = make_ushort4(h0, h1, h2, h3);
        unsigned short l0 = f2bf(v.x - bf2f(h0));
        unsigned short l1 = f2bf(v.y - bf2f(h1));
        unsigned short l2 = f2bf(v.z - bf2f(h2));
        unsigned short l3 = f2bf(v.w - bf2f(h3));
        *(ushort4*)&Al[nd * 104 + kq * 4] = make_ushort4(l0, l1, l2, l3);
    }
}

#define KS_LOOP(PH)                                                                     \
    _Pragma("unroll")                                                                   \
    for (int ks = 0; ks < 3; ++ks) {                                                    \
        const int ko = ks * 32 + g * 8;                                                 \
        bf16x8 a0h = *(const bf16x8*)&Ah[(rb_base + r) * 104 + ko];                     \
        bf16x8 a1h = *(const bf16x8*)&Ah[(rb_base + 16 + r) * 104 + ko];                \
        bf16x8 a0l = *(const bf16x8*)&Al[(rb_base + r) * 104 + ko];                     \
        bf16x8 a1l = *(const bf16x8*)&Al[(rb_base + 16 + r) * 104 + ko];                \
        const unsigned short* bks = bt + ((size_t)(((PH) * 3 + ks) * 6) * 64 + lane) * 8;\
        _Pragma("unroll")                                                               \
        for (int ct = 0; ct < 3; ++ct) {                                                \
            const unsigned short* bp = bks + (size_t)(cg_base + ct) * 512;              \
            bf16x8 bhv = *(const bf16x8*)bp;                                            \
            bf16x8 blv = *(const bf16x8*)(bp + BT_PLANE);                               \
            acc[0][ct] = __builtin_amdgcn_mfma_f32_16x16x32_bf16(a0h, bhv, acc[0][ct], 0, 0, 0); \
            acc[1][ct] = __builtin_amdgcn_mfma_f32_16x16x32_bf16(a1h, bhv, acc[1][ct], 0, 0, 0); \
            acc[0][ct] = __builtin_amdgcn_mfma_f32_16x16x32_bf16(a0l, bhv, acc[0][ct], 0, 0, 0); \
            acc[1][ct] = __builtin_amdgcn_mfma_f32_16x16x32_bf16(a1l, bhv, acc[1][ct], 0, 0, 0); \
            acc[0][ct] = __builtin_amdgcn_mfma_f32_16x16x32_bf16(a0h, blv, acc[0][ct], 0, 0, 0); \
            acc[1][ct] = __builtin_amdgcn_mfma_f32_16x16x32_bf16(a1h, blv, acc[1][ct], 0, 0, 0); \
        }                                                                               \
    }

__global__ __launch_bounds__(256) void layer_fused_kernel(
    const float* __restrict__ h, const int* __restrict__ rs, const int* __restrict__ re,
    const int* __restrict__ col, const unsigned short* __restrict__ bt,
    const float* __restrict__ b, float* __restrict__ out) {
    __shared__ unsigned short Ah[64 * 104];
    __shared__ unsigned short Al[64 * 104];
    const int tid = threadIdx.x;
    const int lane = tid & 63;
    const int w = tid >> 6;
    const int r = lane & 15;
    const int g = lane >> 4;
    const int rb_base = (w >> 1) * 32;
    const int cg_base = (w & 1) * 3;
    const int n0 = blockIdx.x * 64;

    // phase 0 A-operand: gathered neighbor mean, straight to LDS
    gather_to_lds(h, rs, re, col, n0, tid, Ah, Al);

    f32x4 acc[2][3];
#pragma unroll
    for (int i = 0; i < 2; ++i)
#pragma unroll
        for (int j = 0; j < 3; ++j) acc[i][j] = (f32x4){0.f, 0.f, 0.f, 0.f};

    __syncthreads();
    KS_LOOP(0)
    __syncthreads();                       // done reading phase-0 A
    stage_h_to_lds(h, n0, tid, Ah, Al);    // phase 1 A-operand: h tile
    __syncthreads();
    KS_LOOP(1)

    // epilogue: C/D layout: col = lane&15, row = g*4 + j
#pragma unroll
    for (int ct = 0; ct < 3; ++ct) {
        int colc = (cg_base + ct) * 16 + r;
        float bias = b[colc];
#pragma unroll
        for (int rbi = 0; rbi < 2; ++rbi) {
            int row0 = n0 + rb_base + rbi * 16 + g * 4;
#pragma unroll
            for (int j = 0; j < 4; ++j) {
                int node = row0 + j;
                if (node < NNODES)
                    out[(size_t)node * DIM + colc] = fmaxf(acc[rbi][ct][j] + bias, 0.0f);
            }
        }
    }
}

// ---------------- fused gather + layer 2 + final linear (256 threads) ----------------

__global__ __launch_bounds__(256) void layer2_final_kernel(
    const float* __restrict__ h, const int* __restrict__ rs, const int* __restrict__ re,
    const int* __restrict__ col, const unsigned short* __restrict__ bt,
    const float* __restrict__ b, const unsigned short* __restrict__ btl,
    const float* __restrict__ LB, float* __restrict__ out) {
    __shared__ unsigned short Ah[64 * 104];
    __shared__ unsigned short Al[64 * 104];
    const int tid = threadIdx.x;
    const int lane = tid & 63;
    const int w = tid >> 6;
    const int r = lane & 15;
    const int g = lane >> 4;
    const int rb_base = (w >> 1) * 32;
    const int cg_base = (w & 1) * 3;
    const int n0 = blockIdx.x * 64;

    gather_to_lds(h, rs, re, col, n0, tid, Ah, Al);

    f32x4 acc[2][3];
#pragma unroll
    for (int i = 0; i < 2; ++i)
#pragma unroll
        for (int j = 0; j < 3; ++j) acc[i][j] = (f32x4){0.f, 0.f, 0.f, 0.f};

    __syncthreads();
    KS_LOOP(0)
    __syncthreads();
    stage_h_to_lds(h, n0, tid, Ah, Al);
    __syncthreads();
    KS_LOOP(1)

    // h2 = relu(acc+bias) -> LDS bf16 hi/lo, layout [row][k]
    __syncthreads();                       // all waves done reading phase-1 A
#pragma unroll
    for (int ct = 0; ct < 3; ++ct) {
        int colc = (cg_base + ct) * 16 + r;
        float bias = b[colc];
#pragma unroll
        for (int rbi = 0; rbi < 2; ++rbi) {
            int row0 = rb_base + rbi * 16 + g * 4;
#pragma unroll
            for (int j = 0; j < 4; ++j) {
                float v = fmaxf(acc[rbi][ct][j] + bias, 0.0f);
                unsigned short hh = f2bf(v);
                unsigned short ll = f2bf(v - bf2f(hh));
                Ah[(row0 + j) * 104 + colc] = hh;
                Al[(row0 + j) * 104 + colc] = ll;
            }
        }
    }
    __syncthreads();

    // final GEMM: 64 cols, wave = 32 rows x 32 cols, K = 96 (from LDS h2)
    const int cgf = (w & 1) * 2;
    f32x4 accf[2][2];
#pragma unroll
    for (int i = 0; i < 2; ++i)
#pragma unroll
        for (int j = 0; j < 2; ++j) accf[i][j] = (f32x4){0.f, 0.f, 0.f, 0.f};

#pragma unroll
    for (int ks = 0; ks < 3; ++ks) {
        const int ko = ks * 32 + g * 8;
        bf16x8 a0h = *(const bf16x8*)&Ah[(rb_base + r) * 104 + ko];
        bf16x8 a1h = *(const bf16x8*)&Ah[(rb_base + 16 + r) * 104 + ko];
        bf16x8 a0l = *(const bf16x8*)&Al[(rb_base + r) * 104 + ko];
        bf16x8 a1l = *(const bf16x8*)&Al[(rb_base + 16 + r) * 104 + ko];
        const unsigned short* bks = btl + ((size_t)(ks * 4) * 64 + lane) * 8;
#pragma unroll
        for (int ct = 0; ct < 2; ++ct) {
            const unsigned short* bp = bks + (size_t)(cgf + ct) * 512;
            bf16x8 bhv = *(const bf16x8*)bp;
            bf16x8 blv = *(const bf16x8*)(bp + BTL_PLANE);
            accf[0][ct] = __builtin_amdgcn_mfma_f32_16x16x32_bf16(a0h, bhv, accf[0][ct], 0, 0, 0);
            accf[1][ct] = __builtin_amdgcn_mfma_f32_16x16x32_bf16(a1h, bhv, accf[1][ct], 0, 0, 0);
            accf[0][ct] = __builtin_amdgcn_mfma_f32_16x16x32_bf16(a0l, bhv, accf[0][ct], 0, 0, 0);
            accf[1][ct] = __builtin_amdgcn_mfma_f32_16x16x32_bf16(a1l, bhv, accf[1][ct], 0, 0, 0);
            accf[0][ct] = __builtin_amdgcn_mfma_f32_16x16x32_bf16(a0h, blv, accf[0][ct], 0, 0, 0);
            accf[1][ct] = __builtin_amdgcn_mfma_f32_16x16x32_bf16(a1h, blv, accf[1][ct], 0, 0, 0);
        }
    }

#pragma unroll
    for (int ct = 0; ct < 2; ++ct) {
        int colc = (cgf + ct) * 16 + r;
        float bias = LB[colc];
#pragma unroll
        for (int rbi = 0; rbi < 2; ++rbi) {
            int row0 = n0 + rb_base + rbi * 16 + g * 4;
#pragma unroll
            for (int j = 0; j < 4; ++j) {
                int node = row0 + j;
                if (node < NNODES)
                    out[(size_t)node * LLDIM + colc] = accf[rbi][ct][j] + bias;
            }
        }
    }
}

extern "C" void kernel_launch(void* const* d_in, const int* in_sizes, int n_in,
                              void* d_out, int out_size, void* d_ws, size_t ws_size,
                              hipStream_t stream) {
    const float* x     = (const float*)d_in[0];
    const int*   ei    = (const int*)d_in[1];
    const int*   et    = (const int*)d_in[2];
    const float* w1    = (const float*)d_in[3];
    const float* root1 = (const float*)d_in[4];
    const float* b1    = (const float*)d_in[5];
    const float* w2    = (const float*)d_in[6];
    const float* root2 = (const float*)d_in[7];
    const float* b2    = (const float*)d_in[8];
    const float* lin_w = (const float*)d_in[9];
    const float* lin_b = (const float*)d_in[10];

    float* bufA = (float*)d_ws;                      // N*96
    float* bufB = bufA + (size_t)NNODES * DIM;       // N*96
    int* deg       = (int*)(bufB + (size_t)NNODES * DIM);
    int* row_start = deg + SCAN_N;
    int* row_end   = row_start + SCAN_N;
    int* col       = row_end + SCAN_N;               // up to NEDGES
    int* partials  = col + NEDGES;                   // 256
    unsigned short* bt = (unsigned short*)(partials + 256);

    const int edge_blocks = (NEDGES + 255) / 256;
    const int scan_blocks = (SCAN_N + 1023) / 1024;  // 147
    const int node_tiles  = (NNODES + 63) / 64;      // 782
    const int prep_blocks = (SCAN_N + 255) / 256;

    // ---- weight prep + deg zero ----
    prep_kernel<<<prep_blocks, 256, 0, stream>>>(w1, root1, w2, root2, lin_w, bt, deg);

    // ---- CSR build: hist -> scan1 -> fused scan2/3 -> fill ----
    hist_kernel<<<edge_blocks, 256, 0, stream>>>(ei, et, deg);
    scan1_kernel<<<scan_blocks, 256, 0, stream>>>(deg, row_start, partials, SCAN_N);
    scan3_kernel<<<(SCAN_N + 255) / 256, 256, 0, stream>>>(row_start, row_end, partials, SCAN_N);
    fill_kernel<<<edge_blocks, 256, 0, stream>>>(ei, et, row_end, col);

    // ---- Layer 0 (rel 0): x -> bufA ----
    layer_fused_kernel<<<node_tiles, 256, 0, stream>>>(
        x, row_start + 0 * NNODES, row_end + 0 * NNODES, col,
        bt + 0 * (size_t)BT_LAYER, b1, bufA);

    // ---- Layer 1 (rel 1): bufA -> bufB ----
    layer_fused_kernel<<<node_tiles, 256, 0, stream>>>(
        bufA, row_start + 1 * NNODES, row_end + 1 * NNODES, col,
        bt + 1 * (size_t)BT_LAYER, b2, bufB);

    // ---- Layer 2 (rel 2) + final linear: bufB -> d_out ----
    layer2_final_kernel<<<node_tiles, 256, 0, stream>>>(
        bufB, row_start + 2 * NNODES, row_end + 2 * NNODES, col,
        bt + 2 * (size_t)BT_LAYER, b2, bt + BT_LIN_OFF, lin_b, (float*)d_out);
}